// Round 1
// baseline (1077.502 us; speedup 1.0000x reference)
//
#include <hip/hip_runtime.h>

namespace {

constexpr int NXc = 384, NYc = 384, NZc = 48;
constexpr float DXf = 1000.0f, DYf = 1000.0f;
constexpr float DZf = 1.0f / 49.0f;            // 1/(NZ+1)
constexpr float PREFf = 100000.0f, RDf = 287.0f, Gf = 9.81f;

constexpr int PLN  = NYc * NXc;                 // 147456
constexpr int SZ_U = NZc * NYc * (NXc + 1);     // 7,096,320
constexpr int SZ_V = NZc * (NYc + 1) * NXc;     // 7,096,320
constexpr int SZ_W = (NZc - 1) * PLN;           // 6,930,432
constexpr int SZ_T = NZc * PLN;                 // 7,077,888
constexpr int SZ_M = NZc * PLN;
constexpr int SZ_P = (NZc - 1) * PLN;
constexpr int SZ_STATE = SZ_U + SZ_V + SZ_W + SZ_T + SZ_M + SZ_P; // 42,209,280

// ---------------- prep: p (pow-heavy) and Omega, once per point ----------------
__global__ __launch_bounds__(128)
void prep_kernel(const float* __restrict__ Ts, const float* __restrict__ Ms,
                 const float* __restrict__ Ps, const float* __restrict__ Ws,
                 const float* __restrict__ Phit, const float* __restrict__ Phis,
                 float* __restrict__ prs, float* __restrict__ Omg)
{
    const int i = blockIdx.x * blockDim.x + threadIdx.x;
    const int j = blockIdx.y;
    const int k = blockIdx.z;
    if (i >= NXc) return;
    const int jix = j * NXc + i;

    auto PHIP = [&](int kk) -> float {
        if (kk <= 0)   return Phit[jix];
        if (kk >= NZc) return Phis[jix];
        return Ps[(kk - 1) * PLN + jix];
    };

    const float mu  = Ms[k * PLN + jix];
    const float ph0 = PHIP(k), ph1 = PHIP(k + 1);
    const float alpha = -(ph1 - ph0) / DZf / mu;
    const float theta = Ts[k * PLN + jix] / mu;
    const float x  = RDf * theta / PREFf / alpha;
    const float pv = PREFf * powf(x, 1.4f);
    prs[k * PLN + jix] = pv;

    if (k < NZc - 1) {
        const float mu1 = Ms[(k + 1) * PLN + jix];
        const float ph2 = PHIP(k + 2);
        const float alpha1 = -(ph2 - ph1) / DZf / mu1;
        // Omega = -W*G / (bar_z(alpha) * bar_z(Mu))
        const float Om = -Ws[k * PLN + jix] * Gf /
                         ((0.5f * (alpha + alpha1)) * (0.5f * (mu + mu1)));
        Omg[k * PLN + jix] = Om;
    }
}

// ---------------- rhs + RK stage update ----------------
__global__ __launch_bounds__(128)
void rhs_kernel(
    const float* __restrict__ Us, const float* __restrict__ Vs, const float* __restrict__ Ws,
    const float* __restrict__ Ts, const float* __restrict__ Ms, const float* __restrict__ Ps,
    const float* __restrict__ prs, const float* __restrict__ Omg,
    const float* __restrict__ Phit, const float* __restrict__ Phis,
    const float* __restrict__ Pt,   const float* __restrict__ Psrf,
    const float* __restrict__ U0, const float* __restrict__ V0, const float* __restrict__ W0,
    const float* __restrict__ T0, const float* __restrict__ M0, const float* __restrict__ P0,
    float* __restrict__ Uo, float* __restrict__ Vo, float* __restrict__ Wo,
    float* __restrict__ To, float* __restrict__ Mo, float* __restrict__ Po,
    const int* __restrict__ dtp, float coef)
{
    const int i = blockIdx.x * blockDim.x + threadIdx.x;
    const int j = blockIdx.y;
    const int k = blockIdx.z;
    if (i >= NXc) return;
    const float c = coef * (float)(*dtp);

    // ---- accessors (all reads; compiler CSEs duplicates) ----
    auto MU   = [&](int kk, int jj, int ii) -> float { return Ms[(kk * NYc + jj) * NXc + ii]; };
    auto TH   = [&](int kk, int jj, int ii) -> float {
        const int id = (kk * NYc + jj) * NXc + ii; return Ts[id] / Ms[id]; };
    auto PR   = [&](int kk, int jj, int ii) -> float { return prs[(kk * NYc + jj) * NXc + ii]; };
    auto UF   = [&](int kk, int jj, int II) -> float { return Us[(kk * NYc + jj) * (NXc + 1) + II]; };
    auto VF   = [&](int kk, int JJ, int ii) -> float { return Vs[(kk * (NYc + 1) + JJ) * NXc + ii]; };
    auto WF   = [&](int kk, int jj, int ii) -> float { return Ws[(kk * NYc + jj) * NXc + ii]; };
    auto PHIh = [&](int kk, int jj, int ii) -> float { return Ps[(kk * NYc + jj) * NXc + ii]; };
    auto PHIP = [&](int kk, int jj, int ii) -> float {
        if (kk <= 0)   return Phit[jj * NXc + ii];
        if (kk >= NZc) return Phis[jj * NXc + ii];
        return Ps[((kk - 1) * NYc + jj) * NXc + ii]; };
    auto OMP  = [&](int kk, int jj, int ii) -> float {   // pad_z(Omega), levels 0..NZ
        if (kk <= 0 || kk >= NZc) return 0.0f;
        return Omg[((kk - 1) * NYc + jj) * NXc + ii]; };
    auto MUX  = [&](int kk, int jj, int II) -> float {   // x-staggered Mu, II in 0..NX
        const int a = (II == 0) ? NXc - 1 : II - 1;
        const int b = (II == NXc) ? 0 : II;
        return 0.5f * (MU(kk, jj, a) + MU(kk, jj, b)); };
    auto UU   = [&](int kk, int jj, int II) -> float { return UF(kk, jj, II) / MUX(kk, jj, II); };
    auto MUY  = [&](int kk, int JJ, int ii) -> float {   // y-staggered Mu, JJ in 0..NY
        const int a = (JJ == 0) ? NYc - 1 : JJ - 1;
        const int b = (JJ == NYc) ? 0 : JJ;
        return 0.5f * (MU(kk, a, ii) + MU(kk, b, ii)); };
    auto VV   = [&](int kk, int JJ, int ii) -> float { return VF(kk, JJ, ii) / MUY(kk, JJ, ii); };
    auto MUZ  = [&](int kk, int jj, int ii) -> float {   // z-staggered Mu, kk in 0..NZ-2
        return 0.5f * (MU(kk, jj, ii) + MU(kk + 1, jj, ii)); };
    auto WW   = [&](int kk, int jj, int ii) -> float { return WF(kk, jj, ii) / MUZ(kk, jj, ii); };
    auto ALPH = [&](int kk, int jj, int ii) -> float {
        return -(PHIP(kk + 1, jj, ii) - PHIP(kk, jj, ii)) / DZf / MU(kk, jj, ii); };

    // ---- R_U at staggered column II (0..NX) ----
    auto R_U_at = [&](int II) -> float {
        const int kk = k, jj = j;
        const int Im1 = (II - 1 < 0) ? NXc : II - 1;   // wrapped u/U index (-1 -> NX)
        const int Ip1 = (II + 1 > NXc) ? 0 : II + 1;   // (NX+1 -> 0)
        const int xa = (II == 0) ? NXc - 1 : II - 1;   // unstaggered col left
        const int xb = (II == NXc) ? 0 : II;           // unstaggered col right
        const int jm = (jj == 0) ? NYc - 1 : jj - 1;
        const int jp = (jj == NYc - 1) ? 0 : jj + 1;

        const float U_m1 = UF(kk, jj, Im1), U_0 = UF(kk, jj, II), U_p1 = UF(kk, jj, Ip1);
        const float u_m1 = UU(kk, jj, Im1), u_0 = UU(kk, jj, II), u_p1 = UU(kk, jj, Ip1);
        const float rx = -(0.25f * (U_0 + U_p1) * (u_0 + u_p1)
                         - 0.25f * (U_m1 + U_0) * (u_m1 + u_0)) / DXf;

        const float VBj  = 0.5f * (VF(kk, jj,     xa) + VF(kk, jj,     xb));
        const float VBj1 = 0.5f * (VF(kk, jj + 1, xa) + VF(kk, jj + 1, xb));
        const float uyj  = 0.5f * (UU(kk, jm, II) + u_0);
        const float uyj1 = 0.5f * (u_0 + UU(kk, jp, II));
        const float ry = -(VBj1 * uyj1 - VBj * uyj) / DYf;

        const float OBk  = 0.5f * (OMP(kk,     jj, xa) + OMP(kk,     jj, xb));
        const float OBk1 = 0.5f * (OMP(kk + 1, jj, xa) + OMP(kk + 1, jj, xb));
        const float uzk  = (kk == 0)       ? 0.5f * u_0 : 0.5f * (UU(kk - 1, jj, II) + u_0);
        const float uzk1 = (kk == NZc - 1) ? 0.5f * u_0 : 0.5f * (u_0 + UU(kk + 1, jj, II));
        const float rz = -(OBk1 * uzk1 - OBk * uzk) / DZf;

        const float mux = MUX(kk, jj, II);
        const float alx = 0.5f * (ALPH(kk, jj, xa) + ALPH(kk, jj, xb));
        const float dpx = (PR(kk, jj, xb) - PR(kk, jj, xa)) / DXf;
        const float pg1 = -mux * alx * dpx;

        auto PPc = [&](int kh, int col) -> float {      // pad_z(p,P_t,P_s), levels 0..NZ+1
            if (kh <= 0)       return Pt[jj * NXc + col];
            if (kh >= NZc + 1) return Psrf[jj * NXc + col];
            return PR(kh - 1, jj, col); };
        const float pzx_k  = 0.25f * (PPc(kk, xa) + PPc(kk + 1, xa) + PPc(kk, xb) + PPc(kk + 1, xb));
        const float pzx_k1 = 0.25f * (PPc(kk + 1, xa) + PPc(kk + 2, xa) + PPc(kk + 1, xb) + PPc(kk + 2, xb));
        const float dpz = (pzx_k1 - pzx_k) / DZf;
        const float phiz_a = 0.5f * (PHIP(kk, jj, xa) + PHIP(kk + 1, jj, xa));
        const float phiz_b = 0.5f * (PHIP(kk, jj, xb) + PHIP(kk + 1, jj, xb));
        const float pg2 = -dpz * (phiz_b - phiz_a) / DXf;

        return rx + ry + rz + pg1 + pg2;
    };

    // ---- R_V at staggered row JJ (0..NY) ----
    auto R_V_at = [&](int JJ) -> float {
        const int kk = k, ii = i;
        const int Jm1 = (JJ - 1 < 0) ? NYc : JJ - 1;
        const int Jp1 = (JJ + 1 > NYc) ? 0 : JJ + 1;
        const int ya = (JJ == 0) ? NYc - 1 : JJ - 1;
        const int yb = (JJ == NYc) ? 0 : JJ;
        const int im = (ii == 0) ? NXc - 1 : ii - 1;
        const int ip = (ii == NXc - 1) ? 0 : ii + 1;

        const float V_m1 = VF(kk, Jm1, ii), V_0 = VF(kk, JJ, ii), V_p1 = VF(kk, Jp1, ii);
        const float v_m1 = VV(kk, Jm1, ii), v_0 = VV(kk, JJ, ii), v_p1 = VV(kk, Jp1, ii);
        const float ry = -(0.25f * (V_0 + V_p1) * (v_0 + v_p1)
                         - 0.25f * (V_m1 + V_0) * (v_m1 + v_0)) / DYf;

        const float UBi  = 0.5f * (UF(kk, ya, ii)     + UF(kk, yb, ii));
        const float UBi1 = 0.5f * (UF(kk, ya, ii + 1) + UF(kk, yb, ii + 1));
        const float vxi  = 0.5f * (VV(kk, JJ, im) + v_0);
        const float vxi1 = 0.5f * (v_0 + VV(kk, JJ, ip));
        const float rx = -(UBi1 * vxi1 - UBi * vxi) / DXf;

        const float OBk  = 0.5f * (OMP(kk,     ya, ii) + OMP(kk,     yb, ii));
        const float OBk1 = 0.5f * (OMP(kk + 1, ya, ii) + OMP(kk + 1, yb, ii));
        const float vzk  = (kk == 0)       ? 0.5f * v_0 : 0.5f * (VV(kk - 1, JJ, ii) + v_0);
        const float vzk1 = (kk == NZc - 1) ? 0.5f * v_0 : 0.5f * (v_0 + VV(kk + 1, JJ, ii));
        const float rz = -(OBk1 * vzk1 - OBk * vzk) / DZf;

        const float muy = MUY(kk, JJ, ii);
        const float aly = 0.5f * (ALPH(kk, ya, ii) + ALPH(kk, yb, ii));
        const float dpy = (PR(kk, yb, ii) - PR(kk, ya, ii)) / DYf;
        const float pg1 = -muy * aly * dpy;

        auto PPr = [&](int kh, int row) -> float {
            if (kh <= 0)       return Pt[row * NXc + ii];
            if (kh >= NZc + 1) return Psrf[row * NXc + ii];
            return PR(kh - 1, row, ii); };
        const float pzy_k  = 0.25f * (PPr(kk, ya) + PPr(kk + 1, ya) + PPr(kk, yb) + PPr(kk + 1, yb));
        const float pzy_k1 = 0.25f * (PPr(kk + 1, ya) + PPr(kk + 2, ya) + PPr(kk + 1, yb) + PPr(kk + 2, yb));
        const float dpz = (pzy_k1 - pzy_k) / DZf;
        const float phiz_a = 0.5f * (PHIP(kk, ya, ii) + PHIP(kk + 1, ya, ii));
        const float phiz_b = 0.5f * (PHIP(kk, yb, ii) + PHIP(kk + 1, yb, ii));
        const float pg2 = -dpz * (phiz_b - phiz_a) / DYf;

        return rx + ry + rz + pg1 + pg2;
    };

    // ---- R_Theta at (k,j,i) ----
    auto R_T_at = [&]() -> float {
        const int kk = k, jj = j, ii = i;
        const int im = (ii == 0) ? NXc - 1 : ii - 1;
        const int ip = (ii == NXc - 1) ? 0 : ii + 1;
        const int jm = (jj == 0) ? NYc - 1 : jj - 1;
        const int jp = (jj == NYc - 1) ? 0 : jj + 1;
        const float th0 = TH(kk, jj, ii);
        const float rx = -(UF(kk, jj, ii + 1) * 0.5f * (th0 + TH(kk, jj, ip))
                         - UF(kk, jj, ii)     * 0.5f * (TH(kk, jj, im) + th0)) / DXf;
        const float ry = -(VF(kk, jj + 1, ii) * 0.5f * (th0 + TH(kk, jp, ii))
                         - VF(kk, jj, ii)     * 0.5f * (TH(kk, jm, ii) + th0)) / DYf;
        const float Hk  = (kk == 0)       ? 0.0f : OMP(kk, jj, ii)     * 0.5f * (TH(kk - 1, jj, ii) + th0);
        const float Hk1 = (kk == NZc - 1) ? 0.0f : OMP(kk + 1, jj, ii) * 0.5f * (th0 + TH(kk + 1, jj, ii));
        const float rz = -(Hk1 - Hk) / DZf;
        return rx + ry + rz;
    };

    // ---- R_W at (k,j,i), k in 0..NZ-2 ----
    auto R_W_at = [&]() -> float {
        const int kk = k, jj = j, ii = i;
        const int im = (ii == 0) ? NXc - 1 : ii - 1;
        const int ip = (ii == NXc - 1) ? 0 : ii + 1;
        const int jm = (jj == 0) ? NYc - 1 : jj - 1;
        const int jp = (jj == NYc - 1) ? 0 : jj + 1;
        const float w_0 = WW(kk, jj, ii);
        const float Uzi  = 0.5f * (UF(kk, jj, ii)     + UF(kk + 1, jj, ii));
        const float Uzi1 = 0.5f * (UF(kk, jj, ii + 1) + UF(kk + 1, jj, ii + 1));
        const float wxi  = 0.5f * (WW(kk, jj, im) + w_0);
        const float wxi1 = 0.5f * (w_0 + WW(kk, jj, ip));
        const float rx = -(Uzi1 * wxi1 - Uzi * wxi) / DXf;
        const float Vzj  = 0.5f * (VF(kk, jj, ii)     + VF(kk + 1, jj, ii));
        const float Vzj1 = 0.5f * (VF(kk, jj + 1, ii) + VF(kk + 1, jj + 1, ii));
        const float wyj  = 0.5f * (WW(kk, jm, ii) + w_0);
        const float wyj1 = 0.5f * (w_0 + WW(kk, jp, ii));
        const float ry = -(Vzj1 * wyj1 - Vzj * wyj) / DYf;
        const float OZk  = 0.5f * (OMP(kk, jj, ii)     + OMP(kk + 1, jj, ii));
        const float OZk1 = 0.5f * (OMP(kk + 1, jj, ii) + OMP(kk + 2, jj, ii));
        const float wzk  = (kk == 0)       ? 0.5f * w_0 : 0.5f * (WW(kk - 1, jj, ii) + w_0);
        const float wzk1 = (kk == NZc - 2) ? 0.5f * w_0 : 0.5f * (w_0 + WW(kk + 1, jj, ii));
        const float rz = -(OZk1 * wzk1 - OZk * wzk) / DZf;
        const float bu = Gf * ((PR(kk + 1, jj, ii) - PR(kk, jj, ii)) / DZf - MUZ(kk, jj, ii));
        return rx + ry + rz + bu;
    };

    // ---- R_Phi at (k,j,i), k in 0..NZ-2 ----
    auto R_P_at = [&]() -> float {
        const int kk = k, jj = j, ii = i;
        const int im = (ii == 0) ? NXc - 1 : ii - 1;
        const int ip = (ii == NXc - 1) ? 0 : ii + 1;
        const int jm = (jj == 0) ? NYc - 1 : jj - 1;
        const int jp = (jj == NYc - 1) ? 0 : jj + 1;
        const float ubz = 0.25f * (UU(kk, jj, ii) + UU(kk, jj, ii + 1)
                                 + UU(kk + 1, jj, ii) + UU(kk + 1, jj, ii + 1));
        const float dfx = (PHIh(kk, jj, ip) - PHIh(kk, jj, im)) / (2.0f * DXf);
        const float vbz = 0.25f * (VV(kk, jj, ii) + VV(kk, jj + 1, ii)
                                 + VV(kk + 1, jj, ii) + VV(kk + 1, jj + 1, ii));
        const float dfy = (PHIh(kk, jp, ii) - PHIh(kk, jm, ii)) / (2.0f * DYf);
        const float muz = MUZ(kk, jj, ii);
        const float om  = OMP(kk + 1, jj, ii) / muz;     // omega = Omega/bar_z(Mu)
        const float dfz = (PHIP(kk + 2, jj, ii) - PHIP(kk, jj, ii)) / (2.0f * DZf);
        const float w_  = WF(kk, jj, ii) / muz;
        return -ubz * dfx - vbz * dfy - om * dfz + Gf * w_;
    };

    // ---- R_Mu ----
    const float rMu = -(UF(k, j, i + 1) - UF(k, j, i)) / DXf
                      -(VF(k, j + 1, i) - VF(k, j, i)) / DYf
                      -(OMP(k + 1, j, i) - OMP(k, j, i)) / DZf;

    // ---- stage updates from ORIGINAL state ----
    const int idc = (k * NYc + j) * NXc + i;
    To[idc] = T0[idc] + c * R_T_at();
    Mo[idc] = M0[idc] + c * rMu;

    const int idu = (k * NYc + j) * (NXc + 1) + i;
    Uo[idu] = U0[idu] + c * R_U_at(i);
    if (i == NXc - 1) {
        Uo[idu + 1] = U0[idu + 1] + c * R_U_at(NXc);
    }

    const int idv = (k * (NYc + 1) + j) * NXc + i;
    Vo[idv] = V0[idv] + c * R_V_at(j);
    if (j == NYc - 1) {
        const int idv2 = (k * (NYc + 1) + NYc) * NXc + i;
        Vo[idv2] = V0[idv2] + c * R_V_at(NYc);
    }

    if (k < NZc - 1) {
        Wo[idc] = W0[idc] + c * R_W_at();
        Po[idc] = P0[idc] + c * R_P_at();
    }
}

} // anonymous namespace

extern "C" void kernel_launch(void* const* d_in, const int* in_sizes, int n_in,
                              void* d_out, int out_size, void* d_ws, size_t ws_size,
                              hipStream_t stream)
{
    (void)in_sizes; (void)n_in; (void)out_size; (void)ws_size;

    const float* U0   = (const float*)d_in[0];
    const float* V0   = (const float*)d_in[1];
    const float* W0   = (const float*)d_in[2];
    const float* T0   = (const float*)d_in[3];
    const float* M0   = (const float*)d_in[4];
    const float* P0   = (const float*)d_in[5];
    const float* Phit = (const float*)d_in[6];
    const float* Phis = (const float*)d_in[7];
    const float* Pt   = (const float*)d_in[8];
    const float* Psrf = (const float*)d_in[9];
    const int*   dtp  = (const int*)d_in[10];

    float* out = (float*)d_out;
    float* ws  = (float*)d_ws;

    float* outU = out;
    float* outV = outU + SZ_U;
    float* outW = outV + SZ_V;
    float* outT = outW + SZ_W;
    float* outM = outT + SZ_T;
    float* outP = outM + SZ_M;

    float* wsU = ws;
    float* wsV = wsU + SZ_U;
    float* wsW = wsV + SZ_V;
    float* wsT = wsW + SZ_W;
    float* wsM = wsT + SZ_T;
    float* wsP = wsM + SZ_M;

    float* prs = ws + SZ_STATE;       // p  : NZ*NY*NX
    float* Omg = prs + SZ_T;          // Omega : (NZ-1)*NY*NX

    const dim3 blk(128, 1, 1);
    const dim3 grd(NXc / 128, NYc, NZc);

    const float coefs[3] = {1.0f / 3.0f, 0.5f, 1.0f};

    // stage ping-pong: d_in -> d_out -> ws -> d_out
    const float* sU[3] = {U0, outU, wsU};
    const float* sV[3] = {V0, outV, wsV};
    const float* sW[3] = {W0, outW, wsW};
    const float* sT[3] = {T0, outT, wsT};
    const float* sM[3] = {M0, outM, wsM};
    const float* sP[3] = {P0, outP, wsP};
    float* oU[3] = {outU, wsU, outU};
    float* oV[3] = {outV, wsV, outV};
    float* oW[3] = {outW, wsW, outW};
    float* oT[3] = {outT, wsT, outT};
    float* oM[3] = {outM, wsM, outM};
    float* oP[3] = {outP, wsP, outP};

    for (int s = 0; s < 3; ++s) {
        prep_kernel<<<grd, blk, 0, stream>>>(sT[s], sM[s], sP[s], sW[s], Phit, Phis, prs, Omg);
        rhs_kernel<<<grd, blk, 0, stream>>>(
            sU[s], sV[s], sW[s], sT[s], sM[s], sP[s],
            prs, Omg, Phit, Phis, Pt, Psrf,
            U0, V0, W0, T0, M0, P0,
            oU[s], oV[s], oW[s], oT[s], oM[s], oP[s],
            dtp, coefs[s]);
    }
}